// Round 9
// baseline (115.321 us; speedup 1.0000x reference)
//
#include <hip/hip_runtime.h>
#include <math.h>

#define N 8192
#define D 64

typedef short bf16x8 __attribute__((ext_vector_type(8)));
typedef float f32x4 __attribute__((ext_vector_type(4)));
typedef float f32x16 __attribute__((ext_vector_type(16)));

__device__ __forceinline__ void gload_lds16(const void* g, void* l) {
    __builtin_amdgcn_global_load_lds(
        (const __attribute__((address_space(1))) void*)g,
        (__attribute__((address_space(3))) void*)l, 16, 0, 0);
}

// Convert fp32 -> bf16 of (sqrt(log2e)*x); nscl[i] = 0.5*||bf16(s*x)||^2 = log2e*||x||^2/2.
// MFMA on scaled inputs gives log2e*(a.b); exp(-(na+nb-2ab)/2) = exp2(ab' - na' - nb').
// Block 0 also zeroes the accumulator slots + completion counter (8 floats).
__global__ __launch_bounds__(256) void convert_norm(
        const float* __restrict__ X, const float* __restrict__ Y,
        const float* __restrict__ Z,
        unsigned short* __restrict__ bmat, float* __restrict__ nscl,
        float* __restrict__ accs) {
    if (blockIdx.x == 0 && threadIdx.x < 8) accs[threadIdx.x] = 0.0f;
    int wid  = blockIdx.x * 4 + (threadIdx.x >> 6);
    int lane = threadIdx.x & 63;
    int mat  = wid >> 13;
    int row  = wid & 8191;
    const float* src = (mat == 0) ? X : (mat == 1 ? Y : Z);
    float v = src[row * D + lane] * 1.2011224087864498f;  // sqrt(log2(e))
    unsigned int bits = __builtin_bit_cast(unsigned int, v);
    unsigned short us = (unsigned short)((bits + 0x7FFFu + ((bits >> 16) & 1u)) >> 16);
    float f = __builtin_bit_cast(float, (unsigned int)us << 16);
    bmat[(size_t)mat * (N * D) + row * D + lane] = us;
    float sq = f * f;
    #pragma unroll
    for (int off = 32; off; off >>= 1) sq += __shfl_xor(sq, off);
    if (lane == 0) nscl[mat * N + row] = sq * 0.5f;
}

// 2304 blocks of ~32 iterations (64x64 tile each), 32x32x16 MFMA.
// Cross (XZ,XY,YZ): 512 blocks/pair = 128 row strips x 4 col-quarters.
// Self (XX,ZZ,YY): upper triangle; unit i pairs strip i (tiles j=i..127) with
// mirror strip 127-i (j=127-i..127) = 129-tile sequence, split into 4 windows
// [0,33) [33,65) [65,97) [97,129); j(u) = u<seam ? i+u : u-1, seam=128-i;
// weight 2 off tile-diagonal, 1 at u==0 / u==seam. Triple-buffered LDS
// (XOR swizzle), vmcnt(2)+raw-barrier ledger, negligible-tile exp skip.
// The LAST block to finish computes the final scalar (atomic counter).
__global__ __launch_bounds__(256, 6) void gram_kernel(
        const unsigned short* __restrict__ bmat,
        const float* __restrict__ nscl,
        float* accs, unsigned int* cnt, float* out) {
    const int PA[6] = {0, 2, 0, 0, 1, 1};  // X,Z,X,X,Y,Y
    const int PB[6] = {0, 2, 2, 1, 1, 2};  // X,Z,Z,Y,Y,Z

    int bx = blockIdx.x;
    int p, stripI, stripM, seam, u0, u1, jOffA;
    float wBase;
    if (bx < 1536) {                       // cross pairs
        int pc = bx >> 9;                  // 0,1,2 -> p = 2,3,5
        p = (pc == 0) ? 2 : ((pc == 1) ? 3 : 5);
        int bi = bx & 511;
        stripI = bi >> 2; stripM = stripI;
        seam = 1 << 30; jOffA = 0;
        int qt = bi & 3;
        u0 = qt * 32; u1 = u0 + 32;
        wBase = 1.0f;
    } else {                               // self pairs, balanced triangle
        int sx = bx - 1536;
        int ps = sx >> 8;                  // 0,1,2 -> p = 0,1,4
        p = (ps == 0) ? 0 : ((ps == 1) ? 1 : 4);
        int bi = sx & 255;
        int i = bi >> 2, qt = bi & 3;
        stripI = i; stripM = 127 - i;
        seam = 128 - i; jOffA = i;
        u0 = (qt == 0) ? 0 : (1 + qt * 32);
        u1 = 1 + (qt + 1) * 32;
        wBase = 2.0f;
    }

    const unsigned short* A = bmat + (size_t)PA[p] * (N * D);
    const unsigned short* B = bmat + (size_t)PB[p] * (N * D);
    const float* ca = nscl + PA[p] * N;
    const float* cb = nscl + PB[p] * N;

    int tid = threadIdx.x;
    int w = tid >> 6, lane = tid & 63;
    int wr = w >> 1, wc = w & 1;
    int c5 = lane & 31, hk = lane >> 5, r7 = lane & 7;

    __shared__ __align__(128) char lds[3 * 8192];   // triple-buffered 8 KB tiles
    __shared__ float wsum[4];

    // Staging: tile = 64 cols x 128 B contiguous; wave w stages its 2 KB.
    int sub = w * 2048;
    int laneoff = ((lane >> 3) << 7) + ((r7 ^ (lane >> 3)) << 4);
    const char* gBmat = (const char*)B;

    auto tileJ = [&](int u) { return (u < seam) ? (jOffA + u) : (u - 1); };

    // Swizzled ds_read offsets for 32x32x16 B-fragments:
    // lane holds col c5, k = kc*16 + hk*8 + 0..7 -> slot kc*2+hk, phys slot^r7
    int offs[4];
    #pragma unroll
    for (int kc = 0; kc < 4; ++kc)
        offs[kc] = wc * 4096 + c5 * 128 + (((kc * 2 + hk) ^ r7) << 4);

    // Prologue: stage tiles u0, u0+1 into bufs 0, 1
    {
        const char* g0 = gBmat + (size_t)tileJ(u0) * 8192 + sub + laneoff;
        gload_lds16(g0,        lds + sub);
        gload_lds16(g0 + 1024, lds + sub + 1024);
        const char* g1 = gBmat + (size_t)tileJ(u0 + 1) * 8192 + sub + laneoff;
        gload_lds16(g1,        lds + 8192 + sub);
        gload_lds16(g1 + 1024, lds + 8192 + sub + 1024);
    }

    // A fragments (4 k-chunks) + negated row norms for the current strip.
    // C/D row = (reg&3) + 8*(reg>>2) + 4*hk -> ncam[b] covers rows b*8+hk*4+0..3
    bf16x8 afrag[4];
    f32x4 ncam[4];
    auto loadA = [&](int strip) {
        int rowW = strip * 64 + wr * 32;
        #pragma unroll
        for (int kc = 0; kc < 4; ++kc)
            afrag[kc] = *reinterpret_cast<const bf16x8*>(
                A + (size_t)(rowW + c5) * D + kc * 16 + hk * 8);
        #pragma unroll
        for (int b = 0; b < 4; ++b) {
            f32x4 v = *reinterpret_cast<const f32x4*>(ca + rowW + b * 8 + hk * 4);
            ncam[b] = -v;
        }
    };

    f32x4 lsum = (f32x4)0.0f;
    unsigned rb = 0;   // read-buffer byte offset: 0 / 8192 / 16384

    auto doIter = [&](int u) {
        // Tile u landed when all but the newest 2 VMEM events (last iter's
        // stage pair) retired; barrier publishes it block-wide.
        asm volatile("s_waitcnt vmcnt(2)" ::: "memory");
        __builtin_amdgcn_s_barrier();
        asm volatile("" ::: "memory");

        int j = tileJ(u);
        float cb0 = cb[j * 64 + wc * 32 + c5];

        // Stage tile min(u+2, u1-1) into buffer (u+2)%3 (clamped re-stage
        // keeps the vmcnt ledger uniform; that buffer is never read again).
        unsigned sb = rb + 16384; if (sb >= 24576) sb -= 24576;
        int un = (u + 2 <= u1 - 1) ? (u + 2) : (u1 - 1);
        const char* gs = gBmat + (size_t)tileJ(un) * 8192 + sub + laneoff;
        gload_lds16(gs,        lds + sb + sub);
        gload_lds16(gs + 1024, lds + sb + sub + 1024);

        const char* lb = lds + rb;
        bf16x8 bfrag[4];
        #pragma unroll
        for (int kc = 0; kc < 4; ++kc)
            bfrag[kc] = *reinterpret_cast<const bf16x8*>(lb + offs[kc]);

        // C-init carries the norm bias: acc = -(na + nb); result = log2(term)
        f32x16 acc;
        #pragma unroll
        for (int b = 0; b < 4; ++b)
            #pragma unroll
            for (int e = 0; e < 4; ++e)
                acc[b * 4 + e] = ncam[b][e] - cb0;

        #pragma unroll
        for (int kc = 0; kc < 4; ++kc)
            acc = __builtin_amdgcn_mfma_f32_32x32x16_bf16(
                afrag[kc], bfrag[kc], acc, 0, 0, 0);

        // Negligible-tile skip (max3-fusable tree over the 16 lane values)
        float m0 = fmaxf(fmaxf(acc[0],  acc[1]),  acc[2]);
        float m1 = fmaxf(fmaxf(acc[3],  acc[4]),  acc[5]);
        float m2 = fmaxf(fmaxf(acc[6],  acc[7]),  acc[8]);
        float m3 = fmaxf(fmaxf(acc[9],  acc[10]), acc[11]);
        float m4 = fmaxf(fmaxf(acc[12], acc[13]), acc[14]);
        float m5 = fmaxf(fmaxf(m0, m1), m2);
        float m6 = fmaxf(fmaxf(m3, m4), acc[15]);
        float m  = fmaxf(m5, m6);

        if (__any(m > -25.0f)) {
            float fac = ((u == 0) | (u == seam)) ? 1.0f : wBase;
            #pragma unroll
            for (int b = 0; b < 4; ++b) {
                f32x4 ex;
                #pragma unroll
                for (int e = 0; e < 4; ++e)
                    ex[e] = __builtin_amdgcn_exp2f(acc[b * 4 + e]);
                lsum += ex * fac;
            }
        }

        rb += 8192; if (rb >= 24576) rb = 0;
    };

    int s0 = seam; if (s0 < u0) s0 = u0; if (s0 > u1) s0 = u1;
    if (u0 < s0) {
        loadA(stripI);
        for (int u = u0; u < s0; ++u) doIter(u);
    }
    if (s0 < u1) {
        loadA(stripM);
        for (int u = s0; u < u1; ++u) doIter(u);
    }

    float ls = lsum[0] + lsum[1] + lsum[2] + lsum[3];
    #pragma unroll
    for (int off = 32; off; off >>= 1) ls += __shfl_xor(ls, off);
    if (lane == 0) wsum[w] = ls;
    __syncthreads();
    if (tid == 0) {
        atomicAdd(&accs[p], wsum[0] + wsum[1] + wsum[2] + wsum[3]);
        __threadfence();
        unsigned old = atomicAdd(cnt, 1u);
        if (old == 2304u - 1u) {
            __threadfence();
            double s[6];
            #pragma unroll
            for (int i = 0; i < 6; ++i) s[i] = (double)atomicAdd(&accs[i], 0.0f);
            double inv = 1.0 / (8192.0 * 8192.0 * 3.5449077018110318);
            double mxx = s[0] * inv, mzz = s[1] * inv, mxz = s[2] * inv;
            double mxy = s[3] * inv, myy = s[4] * inv, myz = s[5] * inv;
            double r1 = log(3.0 * sqrt(mxx * mzz + 1e-5) / (mxz + 1e-5));
            double r2 = log(3.0 * sqrt(myy * mzz + 1e-5) / (myz + 1e-5));
            double r3 = log(3.0 * sqrt(mxx * myy + 1e-5) / (mxy + 1e-5));
            out[0] = (float)(10.0 * r1 + r2 + 10.0 * r3);
        }
    }
}

extern "C" void kernel_launch(void* const* d_in, const int* in_sizes, int n_in,
                              void* d_out, int out_size, void* d_ws, size_t ws_size,
                              hipStream_t stream) {
    const float* X = (const float*)d_in[0];
    const float* Y = (const float*)d_in[1];
    const float* Z = (const float*)d_in[2];
    char* ws = (char*)d_ws;
    unsigned short* bmat = (unsigned short*)ws;                       // 3 MB
    float* nscl = (float*)(ws + (size_t)3 * N * D * 2);               // 3*8192 f32
    float* accs = (float*)(ws + (size_t)3 * N * D * 2 + (size_t)3 * N * 4); // 8 slots
    unsigned int* cnt = (unsigned int*)(accs + 6);
    float* out = (float*)d_out;

    hipLaunchKernelGGL(convert_norm, dim3(3 * N / 4), dim3(256), 0, stream,
                       X, Y, Z, bmat, nscl, accs);
    hipLaunchKernelGGL(gram_kernel, dim3(2304), dim3(256), 0, stream,
                       bmat, nscl, accs, cnt, out);
}

// Round 10
// 106.396 us; speedup vs baseline: 1.0839x; 1.0839x over previous
//
#include <hip/hip_runtime.h>
#include <math.h>

#define N 8192
#define D 64

typedef short bf16x8 __attribute__((ext_vector_type(8)));
typedef float f32x4 __attribute__((ext_vector_type(4)));

__device__ __forceinline__ void gload_lds16(const void* g, void* l) {
    __builtin_amdgcn_global_load_lds(
        (const __attribute__((address_space(1))) void*)g,
        (__attribute__((address_space(3))) void*)l, 16, 0, 0);
}

// Convert fp32 -> bf16 of (sqrt(log2e)*x); nscl[i] = 0.5*||bf16(s*x)||^2 = log2e*||x||^2/2.
// MFMA on scaled inputs gives log2e*(a.b); exp(-(na+nb-2ab)/2) = exp2(ab' - na' - nb').
// Block 0 also zeroes the accumulator slots + completion counter (8 floats).
__global__ __launch_bounds__(256) void convert_norm(
        const float* __restrict__ X, const float* __restrict__ Y,
        const float* __restrict__ Z,
        unsigned short* __restrict__ bmat, float* __restrict__ nscl,
        float* __restrict__ accs) {
    if (blockIdx.x == 0 && threadIdx.x < 8) accs[threadIdx.x] = 0.0f;
    int wid  = blockIdx.x * 4 + (threadIdx.x >> 6);
    int lane = threadIdx.x & 63;
    int mat  = wid >> 13;
    int row  = wid & 8191;
    const float* src = (mat == 0) ? X : (mat == 1 ? Y : Z);
    float v = src[row * D + lane] * 1.2011224087864498f;  // sqrt(log2(e))
    unsigned int bits = __builtin_bit_cast(unsigned int, v);
    unsigned short us = (unsigned short)((bits + 0x7FFFu + ((bits >> 16) & 1u)) >> 16);
    float f = __builtin_bit_cast(float, (unsigned int)us << 16);
    bmat[(size_t)mat * (N * D) + row * D + lane] = us;
    float sq = f * f;
    #pragma unroll
    for (int off = 32; off; off >>= 1) sq += __shfl_xor(sq, off);
    if (lane == 0) nscl[mat * N + row] = sq * 0.5f;
}

// 2304 blocks of ~32 iterations (64x64 tile each), 16x16x32 MFMA (the
// measured conflict-free LDS read pattern from R6-R8).
// Cross (XZ,XY,YZ): 512 blocks/pair = 128 row strips x 4 col-quarters.
// Self (XX,ZZ,YY): upper triangle; unit i pairs strip i (tiles j=i..127) with
// mirror strip 127-i (j=127-i..127) = 129-tile sequence, split into 4 windows
// [0,33) [33,65) [65,97) [97,129); j(u) = u<seam ? i+u : u-1, seam=128-i;
// weight 2 off tile-diagonal, 1 at u==0 / u==seam. Triple-buffered LDS
// (XOR swizzle), vmcnt(2)+raw-barrier ledger, negligible-tile exp skip.
// The LAST block to finish computes the final scalar (atomic counter).
__global__ __launch_bounds__(256, 6) void gram_kernel(
        const unsigned short* __restrict__ bmat,
        const float* __restrict__ nscl,
        float* accs, unsigned int* cnt, float* out) {
    const int PA[6] = {0, 2, 0, 0, 1, 1};  // X,Z,X,X,Y,Y
    const int PB[6] = {0, 2, 2, 1, 1, 2};  // X,Z,Z,Y,Y,Z

    int bx = blockIdx.x;
    int p, stripI, stripM, seam, u0, u1, jOffA;
    float wBase;
    if (bx < 1536) {                       // cross pairs
        int pc = bx >> 9;                  // 0,1,2 -> p = 2,3,5
        p = (pc == 0) ? 2 : ((pc == 1) ? 3 : 5);
        int bi = bx & 511;
        stripI = bi >> 2; stripM = stripI;
        seam = 1 << 30; jOffA = 0;
        int qt = bi & 3;
        u0 = qt * 32; u1 = u0 + 32;
        wBase = 1.0f;
    } else {                               // self pairs, balanced triangle
        int sx = bx - 1536;
        int ps = sx >> 8;                  // 0,1,2 -> p = 0,1,4
        p = (ps == 0) ? 0 : ((ps == 1) ? 1 : 4);
        int bi = sx & 255;
        int i = bi >> 2, qt = bi & 3;
        stripI = i; stripM = 127 - i;
        seam = 128 - i; jOffA = i;
        u0 = (qt == 0) ? 0 : (1 + qt * 32);
        u1 = 1 + (qt + 1) * 32;
        wBase = 2.0f;
    }

    const unsigned short* A = bmat + (size_t)PA[p] * (N * D);
    const unsigned short* B = bmat + (size_t)PB[p] * (N * D);
    const float* ca = nscl + PA[p] * N;
    const float* cb = nscl + PB[p] * N;

    int tid = threadIdx.x;
    int w = tid >> 6, lane = tid & 63;
    int wr = w >> 1, wc = w & 1;
    int r = lane & 15, q = lane >> 4, r7 = lane & 7;

    __shared__ __align__(128) char lds[3 * 8192];   // triple-buffered 8 KB tiles
    __shared__ float wsum[4];

    // Staging: tile = 64 cols x 128 B contiguous; wave w stages its 2 KB.
    int sub = w * 2048;
    int laneoff = ((lane >> 3) << 7) + ((r7 ^ (lane >> 3)) << 4);
    const char* gBmat = (const char*)B;

    auto tileJ = [&](int u) { return (u < seam) ? (jOffA + u) : (u - 1); };

    // Swizzled ds_read offsets (R6-R8 measured conflict-free):
    // phys(col,slot) holds global slot^(col&7); col = nt*16+r, slot = kc*4+q
    int off0 = wc * 4096 + r * 128 + ((q ^ r7) << 4);        // kc=0
    int off1 = wc * 4096 + r * 128 + (((4 + q) ^ r7) << 4);  // kc=1

    // Prologue: stage tiles u0, u0+1 into bufs 0, 1
    {
        const char* g0 = gBmat + (size_t)tileJ(u0) * 8192 + sub + laneoff;
        gload_lds16(g0,        lds + sub);
        gload_lds16(g0 + 1024, lds + sub + 1024);
        const char* g1 = gBmat + (size_t)tileJ(u0 + 1) * 8192 + sub + laneoff;
        gload_lds16(g1,        lds + 8192 + sub);
        gload_lds16(g1 + 1024, lds + 8192 + sub + 1024);
    }

    // A fragments / negated row norms for the current strip
    bf16x8 afrag[2][2];
    f32x4 ncam[2];
    auto loadA = [&](int strip) {
        int rowBase = strip * 64 + wr * 32;
        #pragma unroll
        for (int mt = 0; mt < 2; ++mt)
            #pragma unroll
            for (int kc = 0; kc < 2; ++kc)
                afrag[mt][kc] = *reinterpret_cast<const bf16x8*>(
                    A + (size_t)(rowBase + mt * 16 + r) * D + kc * 32 + q * 8);
        #pragma unroll
        for (int mt = 0; mt < 2; ++mt)
            #pragma unroll
            for (int e = 0; e < 4; ++e)
                ncam[mt][e] = -ca[rowBase + mt * 16 + q * 4 + e];
    };

    f32x4 lsum = (f32x4)0.0f;
    unsigned rb = 0;   // read-buffer byte offset: 0 / 8192 / 16384

    auto doIter = [&](int u) {
        // Tile u landed when all but the newest 2 VMEM events (last iter's
        // stage pair) retired; barrier publishes it block-wide.
        asm volatile("s_waitcnt vmcnt(2)" ::: "memory");
        __builtin_amdgcn_s_barrier();
        asm volatile("" ::: "memory");

        int j = tileJ(u);
        const float* cbj = cb + j * 64 + wc * 32 + r;
        float cb0 = cbj[0], cb1 = cbj[16];

        // Stage tile min(u+2, u1-1) into buffer (u+2)%3 (clamped re-stage
        // keeps the vmcnt ledger uniform; that buffer is never read again).
        unsigned sb = rb + 16384; if (sb >= 24576) sb -= 24576;
        int un = (u + 2 <= u1 - 1) ? (u + 2) : (u1 - 1);
        const char* gs = gBmat + (size_t)tileJ(un) * 8192 + sub + laneoff;
        gload_lds16(gs,        lds + sb + sub);
        gload_lds16(gs + 1024, lds + sb + sub + 1024);

        const char* lb = lds + rb;
        bf16x8 bfrag[2][2];
        bfrag[0][0] = *reinterpret_cast<const bf16x8*>(lb + off0);
        bfrag[0][1] = *reinterpret_cast<const bf16x8*>(lb + off1);
        bfrag[1][0] = *reinterpret_cast<const bf16x8*>(lb + 2048 + off0);
        bfrag[1][1] = *reinterpret_cast<const bf16x8*>(lb + 2048 + off1);

        // C-init carries the norm bias: acc = -(na + nb); result = log2(term)
        f32x4 acc[2][2];
        acc[0][0] = ncam[0] - cb0; acc[0][1] = ncam[0] - cb1;
        acc[1][0] = ncam[1] - cb0; acc[1][1] = ncam[1] - cb1;

        #pragma unroll
        for (int kc = 0; kc < 2; ++kc)
            #pragma unroll
            for (int mt = 0; mt < 2; ++mt)
                #pragma unroll
                for (int nt = 0; nt < 2; ++nt)
                    acc[mt][nt] = __builtin_amdgcn_mfma_f32_16x16x32_bf16(
                        afrag[mt][kc], bfrag[nt][kc], acc[mt][nt], 0, 0, 0);

        // Negligible-tile skip (max3-fusable tree over the 16 lane values)
        float m0 = fmaxf(fmaxf(acc[0][0][0], acc[0][0][1]), acc[0][0][2]);
        float m1 = fmaxf(fmaxf(acc[0][0][3], acc[0][1][0]), acc[0][1][1]);
        float m2 = fmaxf(fmaxf(acc[0][1][2], acc[0][1][3]), acc[1][0][0]);
        float m3 = fmaxf(fmaxf(acc[1][0][1], acc[1][0][2]), acc[1][0][3]);
        float m4 = fmaxf(fmaxf(acc[1][1][0], acc[1][1][1]), acc[1][1][2]);
        float m5 = fmaxf(fmaxf(m0, m1), m2);
        float m6 = fmaxf(fmaxf(m3, m4), acc[1][1][3]);
        float m  = fmaxf(m5, m6);

        if (__any(m > -25.0f)) {
            float fac = ((u == 0) | (u == seam)) ? 1.0f : wBase;
            #pragma unroll
            for (int mt = 0; mt < 2; ++mt) {
                #pragma unroll
                for (int nt = 0; nt < 2; ++nt) {
                    f32x4 ex;
                    #pragma unroll
                    for (int e = 0; e < 4; ++e)
                        ex[e] = __builtin_amdgcn_exp2f(acc[mt][nt][e]);
                    lsum += ex * fac;
                }
            }
        }

        rb += 8192; if (rb >= 24576) rb = 0;
    };

    int s0 = seam; if (s0 < u0) s0 = u0; if (s0 > u1) s0 = u1;
    if (u0 < s0) {
        loadA(stripI);
        for (int u = u0; u < s0; ++u) doIter(u);
    }
    if (s0 < u1) {
        loadA(stripM);
        for (int u = s0; u < u1; ++u) doIter(u);
    }

    float ls = lsum[0] + lsum[1] + lsum[2] + lsum[3];
    #pragma unroll
    for (int off = 32; off; off >>= 1) ls += __shfl_xor(ls, off);
    if (lane == 0) wsum[w] = ls;
    __syncthreads();
    if (tid == 0) {
        atomicAdd(&accs[p], wsum[0] + wsum[1] + wsum[2] + wsum[3]);
        __threadfence();
        unsigned old = atomicAdd(cnt, 1u);
        if (old == 2304u - 1u) {
            __threadfence();
            double s[6];
            #pragma unroll
            for (int i = 0; i < 6; ++i) s[i] = (double)atomicAdd(&accs[i], 0.0f);
            double inv = 1.0 / (8192.0 * 8192.0 * 3.5449077018110318);
            double mxx = s[0] * inv, mzz = s[1] * inv, mxz = s[2] * inv;
            double mxy = s[3] * inv, myy = s[4] * inv, myz = s[5] * inv;
            double r1 = log(3.0 * sqrt(mxx * mzz + 1e-5) / (mxz + 1e-5));
            double r2 = log(3.0 * sqrt(myy * mzz + 1e-5) / (myz + 1e-5));
            double r3 = log(3.0 * sqrt(mxx * myy + 1e-5) / (mxy + 1e-5));
            out[0] = (float)(10.0 * r1 + r2 + 10.0 * r3);
        }
    }
}

extern "C" void kernel_launch(void* const* d_in, const int* in_sizes, int n_in,
                              void* d_out, int out_size, void* d_ws, size_t ws_size,
                              hipStream_t stream) {
    const float* X = (const float*)d_in[0];
    const float* Y = (const float*)d_in[1];
    const float* Z = (const float*)d_in[2];
    char* ws = (char*)d_ws;
    unsigned short* bmat = (unsigned short*)ws;                       // 3 MB
    float* nscl = (float*)(ws + (size_t)3 * N * D * 2);               // 3*8192 f32
    float* accs = (float*)(ws + (size_t)3 * N * D * 2 + (size_t)3 * N * 4); // 8 slots
    unsigned int* cnt = (unsigned int*)(accs + 6);
    float* out = (float*)d_out;

    hipLaunchKernelGGL(convert_norm, dim3(3 * N / 4), dim3(256), 0, stream,
                       X, Y, Z, bmat, nscl, accs);
    hipLaunchKernelGGL(gram_kernel, dim3(2304), dim3(256), 0, stream,
                       bmat, nscl, accs, cnt, out);
}

// Round 11
// 89.606 us; speedup vs baseline: 1.2870x; 1.1874x over previous
//
#include <hip/hip_runtime.h>
#include <math.h>

#define N 8192
#define D 64

typedef short bf16x8 __attribute__((ext_vector_type(8)));
typedef float f32x4 __attribute__((ext_vector_type(4)));

__device__ __forceinline__ void gload_lds16(const void* g, void* l) {
    __builtin_amdgcn_global_load_lds(
        (const __attribute__((address_space(1))) void*)g,
        (__attribute__((address_space(3))) void*)l, 16, 0, 0);
}
__device__ __forceinline__ void gload_lds4(const void* g, void* l) {
    __builtin_amdgcn_global_load_lds(
        (const __attribute__((address_space(1))) void*)g,
        (__attribute__((address_space(3))) void*)l, 4, 0, 0);
}

// Convert fp32 -> bf16 of (sqrt(log2e)*x); nscl[i] = 0.5*||bf16(s*x)||^2 = log2e*||x||^2/2.
// MFMA on scaled inputs gives log2e*(a.b); exp(-(na+nb-2ab)/2) = exp2(ab' - na' - nb').
// Block 0 also zeroes the accumulator slots + completion counter (8 floats).
__global__ __launch_bounds__(256) void convert_norm(
        const float* __restrict__ X, const float* __restrict__ Y,
        const float* __restrict__ Z,
        unsigned short* __restrict__ bmat, float* __restrict__ nscl,
        float* __restrict__ accs) {
    if (blockIdx.x == 0 && threadIdx.x < 8) accs[threadIdx.x] = 0.0f;
    int wid  = blockIdx.x * 4 + (threadIdx.x >> 6);
    int lane = threadIdx.x & 63;
    int mat  = wid >> 13;
    int row  = wid & 8191;
    const float* src = (mat == 0) ? X : (mat == 1 ? Y : Z);
    float v = src[row * D + lane] * 1.2011224087864498f;  // sqrt(log2(e))
    unsigned int bits = __builtin_bit_cast(unsigned int, v);
    unsigned short us = (unsigned short)((bits + 0x7FFFu + ((bits >> 16) & 1u)) >> 16);
    float f = __builtin_bit_cast(float, (unsigned int)us << 16);
    bmat[(size_t)mat * (N * D) + row * D + lane] = us;
    float sq = f * f;
    #pragma unroll
    for (int off = 32; off; off >>= 1) sq += __shfl_xor(sq, off);
    if (lane == 0) nscl[mat * N + row] = sq * 0.5f;
}

// 1536 blocks = 6 pairs x 128 row-strips x 2 col-halves: EXACTLY 6 blocks/CU
// resident (the measured-best R6 configuration: zero tail, uniform 64 iters).
// Per iter: tile (8 KB, 2x gload_lds16) AND the 64 col-norm floats (256 B,
// 1x gload_lds4) are staged into a triple-buffered LDS ring -> the loop body
// has ZERO global loads into VGPRs; the only VMEM gate is the counted ledger
// s_waitcnt vmcnt(3) + raw s_barrier (3 VMEM/iter/wave, all for tile u+2).
// XOR store/read swizzle on the tile (measured conflict-free R6-R8/R10);
// cb ds_read is 4-lane same-address broadcast (free). Negligible tiles
// (all acc < -25) skip the exp epilogue. Last finishing block finalizes.
__global__ __launch_bounds__(256, 6) void gram_kernel(
        const unsigned short* __restrict__ bmat,
        const float* __restrict__ nscl,
        float* accs, unsigned int* cnt, float* out) {
    const int PA[6] = {0, 2, 0, 0, 1, 1};  // X,Z,X,X,Y,Y
    const int PB[6] = {0, 2, 2, 1, 1, 2};  // X,Z,Z,Y,Y,Z
    int bx = blockIdx.x;
    int p  = bx >> 8;             // 0..5
    int bi = bx & 255;
    int ti = bi >> 1;             // row strip (64 rows)
    int tc = bi & 1;              // col half (4096 cols)

    const unsigned short* A = bmat + (size_t)PA[p] * (N * D);
    const unsigned short* B = bmat + (size_t)PB[p] * (N * D);
    const float* ca = nscl + PA[p] * N;
    const float* cb = nscl + PB[p] * N;

    int tid = threadIdx.x;
    int w = tid >> 6, lane = tid & 63;
    int wr = w >> 1, wc = w & 1;
    int rowBase = ti * 64 + wr * 32;
    int r = lane & 15, q = lane >> 4, r7 = lane & 7;

    // 3 x 8 KB tile ring + 3 x 256 B cb ring + 4 floats wsum = 25360 B
    __shared__ __align__(128) char lds[3 * 8192 + 3 * 256 + 16];
    char* cbuf = lds + 24576;
    float* wsum = (float*)(lds + 24576 + 768);

    // Staging: tile = 64 cols x 128 B contiguous; wave w stages its 2 KB.
    int sub = w * 2048;
    int laneoff = ((lane >> 3) << 7) + ((r7 ^ (lane >> 3)) << 4);
    const char* gB  = (const char*)(B + (size_t)(tc * 4096) * D);
    const char* gCb = (const char*)(cb + tc * 4096);

    // Swizzled ds_read offsets (measured conflict-free):
    // phys(col,slot) holds global slot^(col&7); col = nt*16+r, slot = kc*4+q
    int off0 = wc * 4096 + r * 128 + ((q ^ r7) << 4);        // kc=0
    int off1 = wc * 4096 + r * 128 + (((4 + q) ^ r7) << 4);  // kc=1

    // Prologue: stage tiles 0,1 (+cb) into ring slots 0,1  -> 6 VMEM/wave
    {
        const char* g0 = gB + sub + laneoff;
        gload_lds16(g0,        lds + sub);
        gload_lds16(g0 + 1024, lds + sub + 1024);
        gload_lds4(gCb + (size_t)lane * 4, cbuf);
        const char* g1 = gB + 8192 + sub + laneoff;
        gload_lds16(g1,        lds + 8192 + sub);
        gload_lds16(g1 + 1024, lds + 8192 + sub + 1024);
        gload_lds4(gCb + 256 + (size_t)lane * 4, cbuf + 256);
    }

    // Loop-invariant A fragments and negated row-norm constants
    bf16x8 afrag[2][2];
    #pragma unroll
    for (int mt = 0; mt < 2; ++mt)
        #pragma unroll
        for (int kc = 0; kc < 2; ++kc)
            afrag[mt][kc] = *reinterpret_cast<const bf16x8*>(
                A + (size_t)(rowBase + mt * 16 + r) * D + kc * 32 + q * 8);
    f32x4 ncam[2];
    #pragma unroll
    for (int mt = 0; mt < 2; ++mt)
        #pragma unroll
        for (int e = 0; e < 4; ++e)
            ncam[mt][e] = -ca[rowBase + mt * 16 + q * 4 + e];

    f32x4 lsum = (f32x4)0.0f;
    unsigned rb = 0;   // read slot byte offset: 0 / 8192 / 16384

    for (int t = 0; t < 64; ++t) {
        // Tile t (and its cb) landed when all but the newest 3 VMEM events
        // (last iter's stage triple) retired; barrier publishes block-wide.
        asm volatile("s_waitcnt vmcnt(3)" ::: "memory");
        __builtin_amdgcn_s_barrier();
        asm volatile("" ::: "memory");

        // Stage tile min(t+2,63) into ring slot (t+2)%3 (clamped re-stage
        // keeps the vmcnt ledger uniform; that slot is never read again).
        unsigned sb = rb + 16384; if (sb >= 24576) sb -= 24576;
        int tn = (t + 2 <= 63) ? (t + 2) : 63;
        const char* gs = gB + (size_t)tn * 8192 + sub + laneoff;
        gload_lds16(gs,        lds + sb + sub);
        gload_lds16(gs + 1024, lds + sb + sub + 1024);
        gload_lds4(gCb + (size_t)tn * 256 + (size_t)lane * 4,
                   cbuf + ((sb >> 13) << 8));

        // cb from LDS (broadcast pattern, free) + swizzled B fragments
        const float* cbL = (const float*)(cbuf + ((rb >> 13) << 8));
        float cb0 = cbL[wc * 32 + r];
        float cb1 = cbL[wc * 32 + 16 + r];

        const char* lb = lds + rb;
        bf16x8 bfrag[2][2];
        bfrag[0][0] = *reinterpret_cast<const bf16x8*>(lb + off0);
        bfrag[0][1] = *reinterpret_cast<const bf16x8*>(lb + off1);
        bfrag[1][0] = *reinterpret_cast<const bf16x8*>(lb + 2048 + off0);
        bfrag[1][1] = *reinterpret_cast<const bf16x8*>(lb + 2048 + off1);

        // C-init carries the norm bias: acc = -(na + nb); result = log2(term)
        f32x4 acc[2][2];
        acc[0][0] = ncam[0] - cb0; acc[0][1] = ncam[0] - cb1;
        acc[1][0] = ncam[1] - cb0; acc[1][1] = ncam[1] - cb1;

        #pragma unroll
        for (int kc = 0; kc < 2; ++kc)
            #pragma unroll
            for (int mt = 0; mt < 2; ++mt)
                #pragma unroll
                for (int nt = 0; nt < 2; ++nt)
                    acc[mt][nt] = __builtin_amdgcn_mfma_f32_16x16x32_bf16(
                        afrag[mt][kc], bfrag[nt][kc], acc[mt][nt], 0, 0, 0);

        // Negligible-tile skip (max3-fusable tree over the 16 lane values)
        float m0 = fmaxf(fmaxf(acc[0][0][0], acc[0][0][1]), acc[0][0][2]);
        float m1 = fmaxf(fmaxf(acc[0][0][3], acc[0][1][0]), acc[0][1][1]);
        float m2 = fmaxf(fmaxf(acc[0][1][2], acc[0][1][3]), acc[1][0][0]);
        float m3 = fmaxf(fmaxf(acc[1][0][1], acc[1][0][2]), acc[1][0][3]);
        float m4 = fmaxf(fmaxf(acc[1][1][0], acc[1][1][1]), acc[1][1][2]);
        float m5 = fmaxf(fmaxf(m0, m1), m2);
        float m6 = fmaxf(fmaxf(m3, m4), acc[1][1][3]);
        float m  = fmaxf(m5, m6);

        if (__any(m > -25.0f)) {
            #pragma unroll
            for (int mt = 0; mt < 2; ++mt) {
                #pragma unroll
                for (int nt = 0; nt < 2; ++nt) {
                    f32x4 ex;
                    #pragma unroll
                    for (int e = 0; e < 4; ++e)
                        ex[e] = __builtin_amdgcn_exp2f(acc[mt][nt][e]);
                    lsum += ex;
                }
            }
        }

        rb += 8192; if (rb >= 24576) rb = 0;
    }

    float ls = lsum[0] + lsum[1] + lsum[2] + lsum[3];
    #pragma unroll
    for (int off = 32; off; off >>= 1) ls += __shfl_xor(ls, off);
    if (lane == 0) wsum[w] = ls;
    __syncthreads();
    if (tid == 0) {
        atomicAdd(&accs[p], wsum[0] + wsum[1] + wsum[2] + wsum[3]);
        __threadfence();
        unsigned old = atomicAdd(cnt, 1u);
        if (old == 1536u - 1u) {
            __threadfence();
            double s[6];
            #pragma unroll
            for (int i = 0; i < 6; ++i) s[i] = (double)atomicAdd(&accs[i], 0.0f);
            double inv = 1.0 / (8192.0 * 8192.0 * 3.5449077018110318);
            double mxx = s[0] * inv, mzz = s[1] * inv, mxz = s[2] * inv;
            double mxy = s[3] * inv, myy = s[4] * inv, myz = s[5] * inv;
            double r1 = log(3.0 * sqrt(mxx * mzz + 1e-5) / (mxz + 1e-5));
            double r2 = log(3.0 * sqrt(myy * mzz + 1e-5) / (myz + 1e-5));
            double r3 = log(3.0 * sqrt(mxx * myy + 1e-5) / (mxy + 1e-5));
            out[0] = (float)(10.0 * r1 + r2 + 10.0 * r3);
        }
    }
}

extern "C" void kernel_launch(void* const* d_in, const int* in_sizes, int n_in,
                              void* d_out, int out_size, void* d_ws, size_t ws_size,
                              hipStream_t stream) {
    const float* X = (const float*)d_in[0];
    const float* Y = (const float*)d_in[1];
    const float* Z = (const float*)d_in[2];
    char* ws = (char*)d_ws;
    unsigned short* bmat = (unsigned short*)ws;                       // 3 MB
    float* nscl = (float*)(ws + (size_t)3 * N * D * 2);               // 3*8192 f32
    float* accs = (float*)(ws + (size_t)3 * N * D * 2 + (size_t)3 * N * 4); // 8 slots
    unsigned int* cnt = (unsigned int*)(accs + 6);
    float* out = (float*)d_out;

    hipLaunchKernelGGL(convert_norm, dim3(3 * N / 4), dim3(256), 0, stream,
                       X, Y, Z, bmat, nscl, accs);
    hipLaunchKernelGGL(gram_kernel, dim3(1536), dim3(256), 0, stream,
                       bmat, nscl, accs, cnt, out);
}

// Round 12
// 83.094 us; speedup vs baseline: 1.3878x; 1.0784x over previous
//
#include <hip/hip_runtime.h>
#include <math.h>

#define N 8192
#define D 64

typedef short bf16x8 __attribute__((ext_vector_type(8)));
typedef float f32x4 __attribute__((ext_vector_type(4)));

__device__ __forceinline__ void gload_lds16(const void* g, void* l) {
    __builtin_amdgcn_global_load_lds(
        (const __attribute__((address_space(1))) void*)g,
        (__attribute__((address_space(3))) void*)l, 16, 0, 0);
}

__global__ void init_accs(float* accs) {
    if (threadIdx.x < 6) accs[threadIdx.x] = 0.0f;
}

// Convert fp32 -> bf16 of (sqrt(log2e)*x); nscl[i] = 0.5*||bf16(s*x)||^2 = log2e*||x||^2/2.
// MFMA on scaled inputs gives log2e*(a.b); exp(-(na+nb-2ab)/2) = exp2(ab' - na' - nb').
__global__ __launch_bounds__(256) void convert_norm(
        const float* __restrict__ X, const float* __restrict__ Y,
        const float* __restrict__ Z,
        unsigned short* __restrict__ bmat, float* __restrict__ nscl) {
    int wid  = blockIdx.x * 4 + (threadIdx.x >> 6);
    int lane = threadIdx.x & 63;
    int mat  = wid >> 13;
    int row  = wid & 8191;
    const float* src = (mat == 0) ? X : (mat == 1 ? Y : Z);
    float v = src[row * D + lane] * 1.2011224087864498f;  // sqrt(log2(e))
    unsigned int bits = __builtin_bit_cast(unsigned int, v);
    unsigned short us = (unsigned short)((bits + 0x7FFFu + ((bits >> 16) & 1u)) >> 16);
    float f = __builtin_bit_cast(float, (unsigned int)us << 16);
    bmat[(size_t)mat * (N * D) + row * D + lane] = us;
    float sq = f * f;
    #pragma unroll
    for (int off = 32; off; off >>= 1) sq += __shfl_xor(sq, off);
    if (lane == 0) nscl[mat * N + row] = sq * 0.5f;
}

// Block: 64 rows x 4096 cols of one pair; 64 iters of 64-col tiles (8 KB).
// Cooperative staging into TRIPLE-buffered LDS (XOR swizzle), synced per iter
// by s_waitcnt vmcnt(2) + raw s_barrier (stage loads stay in flight across
// the barrier). Negligible tiles (all acc < -30 -> every term < 1e-9) skip
// the exp epilogue. EXACT R6 structure (measured best); only thr changed.
__global__ __launch_bounds__(256, 6) void gram_kernel(
        const unsigned short* __restrict__ bmat,
        const float* __restrict__ nscl,
        float* __restrict__ accs) {
    const int PA[6] = {0, 2, 0, 0, 1, 1};  // X,Z,X,X,Y,Y
    const int PB[6] = {0, 2, 2, 1, 1, 2};  // X,Z,Z,Y,Y,Z
    int p  = blockIdx.y;
    int bx = blockIdx.x;          // 0..255
    int ti = bx >> 1;             // row strip (64 rows)
    int tc = bx & 1;              // col half (4096 cols)

    const unsigned short* A = bmat + (size_t)PA[p] * (N * D);
    const unsigned short* B = bmat + (size_t)PB[p] * (N * D);
    const float* ca = nscl + PA[p] * N;
    const float* cb = nscl + PB[p] * N;

    int tid = threadIdx.x;
    int w = tid >> 6, lane = tid & 63;
    int wr = w >> 1, wc = w & 1;
    int rowBase = ti * 64 + wr * 32;
    int r = lane & 15, q = lane >> 4, r7 = lane & 7;

    __shared__ __align__(128) char lds[3 * 8192];   // triple-buffered 8 KB tiles
    __shared__ float wsum[4];

    // Staging: tile = 64 cols x 128 B contiguous; wave w stages sub-region.
    // Inverse-swizzled source; LDS dest linear (granule l*16).
    int sub = w * 2048;
    int laneoff = ((lane >> 3) << 7) + ((r7 ^ (lane >> 3)) << 4);
    const char* gB = (const char*)(B + (size_t)(tc * 4096) * D);

    // Swizzled ds_read offsets: phys(col,slot) holds global slot^(col&7)
    int off0 = wc * 4096 + r * 128 + ((q ^ r7) << 4);        // kc=0
    int off1 = wc * 4096 + r * 128 + (((4 + q) ^ r7) << 4);  // kc=1

    // Prologue: stage tiles 0,1 into bufs 0,1 (4 loads/wave outstanding)
    {
        const char* g0 = gB + sub + laneoff;
        gload_lds16(g0,        lds + sub);
        gload_lds16(g0 + 1024, lds + sub + 1024);
        const char* g1 = gB + 8192 + sub + laneoff;
        gload_lds16(g1,        lds + 8192 + sub);
        gload_lds16(g1 + 1024, lds + 8192 + sub + 1024);
    }

    // Loop-invariant A fragments and negated row-norm constants
    bf16x8 afrag[2][2];
    #pragma unroll
    for (int mt = 0; mt < 2; ++mt)
        #pragma unroll
        for (int kc = 0; kc < 2; ++kc)
            afrag[mt][kc] = *reinterpret_cast<const bf16x8*>(
                A + (size_t)(rowBase + mt * 16 + r) * D + kc * 32 + q * 8);
    f32x4 ncam[2];
    #pragma unroll
    for (int mt = 0; mt < 2; ++mt)
        #pragma unroll
        for (int e = 0; e < 4; ++e)
            ncam[mt][e] = -ca[rowBase + mt * 16 + q * 4 + e];

    const float* cbp = cb + tc * 4096 + wc * 32 + r;

    f32x4 lsum = (f32x4)0.0f;
    unsigned rb = 0;   // read-buffer byte offset: 0 / 8192 / 16384

    for (int t = 0; t < 64; ++t) {
        // Tile t landed when all but the newest 2 VMEM events (last iter's
        // stage pair) retired; barrier publishes it block-wide.
        asm volatile("s_waitcnt vmcnt(2)" ::: "memory");
        __builtin_amdgcn_s_barrier();
        asm volatile("" ::: "memory");

        // cb loads FIRST (so they retire before this iter's stage loads)
        float cb0 = cbp[0], cb1 = cbp[16];

        // Stage tile min(t+2,63) into buffer (t+2)%3 (clamped re-stage keeps
        // the vmcnt ledger uniform; its buffer is never read again).
        unsigned sb = rb + 16384; if (sb >= 24576) sb -= 24576;
        int tn = (t + 2 <= 63) ? (t + 2) : 63;
        const char* gs = gB + (size_t)tn * 8192 + sub + laneoff;
        gload_lds16(gs,        lds + sb + sub);
        gload_lds16(gs + 1024, lds + sb + sub + 1024);

        const char* lb = lds + rb;
        bf16x8 bfrag[2][2];
        bfrag[0][0] = *reinterpret_cast<const bf16x8*>(lb + off0);
        bfrag[0][1] = *reinterpret_cast<const bf16x8*>(lb + off1);
        bfrag[1][0] = *reinterpret_cast<const bf16x8*>(lb + 2048 + off0);
        bfrag[1][1] = *reinterpret_cast<const bf16x8*>(lb + 2048 + off1);

        // C-init carries the norm bias: acc = -(na + nb); result = log2(term)
        f32x4 acc[2][2];
        acc[0][0] = ncam[0] - cb0; acc[0][1] = ncam[0] - cb1;
        acc[1][0] = ncam[1] - cb0; acc[1][1] = ncam[1] - cb1;

        #pragma unroll
        for (int kc = 0; kc < 2; ++kc)
            #pragma unroll
            for (int mt = 0; mt < 2; ++mt)
                #pragma unroll
                for (int nt = 0; nt < 2; ++nt)
                    acc[mt][nt] = __builtin_amdgcn_mfma_f32_16x16x32_bf16(
                        afrag[mt][kc], bfrag[nt][kc], acc[mt][nt], 0, 0, 0);

        // Negligible-tile skip: every term < 2^-30 -> total error ~1e-7
        f32x4 vm = acc[0][0];
        #pragma unroll
        for (int mt = 0; mt < 2; ++mt)
            #pragma unroll
            for (int nt = 0; nt < 2; ++nt)
                if (mt | nt)
                    #pragma unroll
                    for (int e = 0; e < 4; ++e)
                        vm[e] = fmaxf(vm[e], acc[mt][nt][e]);
        float m = fmaxf(fmaxf(vm[0], vm[1]), fmaxf(vm[2], vm[3]));

        if (__any(m > -30.0f)) {
            #pragma unroll
            for (int mt = 0; mt < 2; ++mt) {
                #pragma unroll
                for (int nt = 0; nt < 2; ++nt) {
                    f32x4 ex;
                    #pragma unroll
                    for (int e = 0; e < 4; ++e)
                        ex[e] = __builtin_amdgcn_exp2f(acc[mt][nt][e]);
                    lsum += ex;
                }
            }
        }

        cbp += 64;
        rb += 8192; if (rb >= 24576) rb = 0;
    }

    float ls = lsum[0] + lsum[1] + lsum[2] + lsum[3];
    #pragma unroll
    for (int off = 32; off; off >>= 1) ls += __shfl_xor(ls, off);
    if (lane == 0) wsum[w] = ls;
    __syncthreads();
    if (tid == 0)
        atomicAdd(&accs[p], wsum[0] + wsum[1] + wsum[2] + wsum[3]);
}

__global__ void finalize_kernel(const float* __restrict__ accs,
                                float* __restrict__ out) {
    double inv = 1.0 / (8192.0 * 8192.0 * 3.5449077018110318);
    double mxx = accs[0] * inv, mzz = accs[1] * inv, mxz = accs[2] * inv;
    double mxy = accs[3] * inv, myy = accs[4] * inv, myz = accs[5] * inv;
    double r1 = log(3.0 * sqrt(mxx * mzz + 1e-5) / (mxz + 1e-5));
    double r2 = log(3.0 * sqrt(myy * mzz + 1e-5) / (myz + 1e-5));
    double r3 = log(3.0 * sqrt(mxx * myy + 1e-5) / (mxy + 1e-5));
    out[0] = (float)(10.0 * r1 + r2 + 10.0 * r3);
}

extern "C" void kernel_launch(void* const* d_in, const int* in_sizes, int n_in,
                              void* d_out, int out_size, void* d_ws, size_t ws_size,
                              hipStream_t stream) {
    const float* X = (const float*)d_in[0];
    const float* Y = (const float*)d_in[1];
    const float* Z = (const float*)d_in[2];
    char* ws = (char*)d_ws;
    unsigned short* bmat = (unsigned short*)ws;                       // 3 MB
    float* nscl = (float*)(ws + (size_t)3 * N * D * 2);               // 3*8192 f32
    float* accs = (float*)(ws + (size_t)3 * N * D * 2 + (size_t)3 * N * 4);
    float* out = (float*)d_out;

    hipLaunchKernelGGL(init_accs, dim3(1), dim3(64), 0, stream, accs);
    hipLaunchKernelGGL(convert_norm, dim3(3 * N / 4), dim3(256), 0, stream,
                       X, Y, Z, bmat, nscl);
    hipLaunchKernelGGL(gram_kernel, dim3(256, 6), dim3(256), 0, stream,
                       bmat, nscl, accs);
    hipLaunchKernelGGL(finalize_kernel, dim3(1), dim3(1), 0, stream, accs, out);
}

// Round 13
// 79.479 us; speedup vs baseline: 1.4510x; 1.0455x over previous
//
#include <hip/hip_runtime.h>
#include <math.h>

#define N 8192
#define D 64

typedef short bf16x8 __attribute__((ext_vector_type(8)));
typedef float f32x4 __attribute__((ext_vector_type(4)));

__device__ __forceinline__ void gload_lds16(const void* g, void* l) {
    __builtin_amdgcn_global_load_lds(
        (const __attribute__((address_space(1))) void*)g,
        (__attribute__((address_space(3))) void*)l, 16, 0, 0);
}

__global__ void init_accs(float* accs) {
    if (threadIdx.x < 6) accs[threadIdx.x] = 0.0f;
}

// Convert fp32 -> bf16 of (sqrt(log2e)*x); nscl[i] = 0.5*||bf16(s*x)||^2 = log2e*||x||^2/2.
__global__ __launch_bounds__(256) void convert_norm(
        const float* __restrict__ X, const float* __restrict__ Y,
        const float* __restrict__ Z,
        unsigned short* __restrict__ bmat, float* __restrict__ nscl) {
    int wid  = blockIdx.x * 4 + (threadIdx.x >> 6);
    int lane = threadIdx.x & 63;
    int mat  = wid >> 13;
    int row  = wid & 8191;
    const float* src = (mat == 0) ? X : (mat == 1 ? Y : Z);
    float v = src[row * D + lane] * 1.2011224087864498f;  // sqrt(log2(e))
    unsigned int bits = __builtin_bit_cast(unsigned int, v);
    unsigned short us = (unsigned short)((bits + 0x7FFFu + ((bits >> 16) & 1u)) >> 16);
    float f = __builtin_bit_cast(float, (unsigned int)us << 16);
    bmat[(size_t)mat * (N * D) + row * D + lane] = us;
    float sq = f * f;
    #pragma unroll
    for (int off = 32; off; off >>= 1) sq += __shfl_xor(sq, off);
    if (lane == 0) nscl[mat * N + row] = sq * 0.5f;
}

// R12 skeleton (measured best: 1536 uniform blocks, triple-buffer ring,
// vmcnt(2)+raw-barrier ledger, thr=-30 skip) with ONE change: the register-
// only epilogue (max-tree + exp) of tile t is PIPELINED to after barrier t+1,
// filling the ds_read/cb latency shadow. Three named acc sets (one per ring
// slot, all compile-time indexed) carry state across the barrier; loop is
// unrolled by 3 so rb/sb/ds offsets are immediates.
__global__ __launch_bounds__(256, 6) void gram_kernel(
        const unsigned short* __restrict__ bmat,
        const float* __restrict__ nscl,
        float* __restrict__ accs) {
    const int PA[6] = {0, 2, 0, 0, 1, 1};  // X,Z,X,X,Y,Y
    const int PB[6] = {0, 2, 2, 1, 1, 2};  // X,Z,Z,Y,Y,Z
    int p  = blockIdx.y;
    int bx = blockIdx.x;          // 0..255
    int ti = bx >> 1;             // row strip (64 rows)
    int tc = bx & 1;              // col half (4096 cols)

    const unsigned short* A = bmat + (size_t)PA[p] * (N * D);
    const unsigned short* B = bmat + (size_t)PB[p] * (N * D);
    const float* ca = nscl + PA[p] * N;
    const float* cb = nscl + PB[p] * N;

    int tid = threadIdx.x;
    int w = tid >> 6, lane = tid & 63;
    int wr = w >> 1, wc = w & 1;
    int rowBase = ti * 64 + wr * 32;
    int r = lane & 15, q = lane >> 4, r7 = lane & 7;

    __shared__ __align__(128) char lds[3 * 8192];   // triple-buffered 8 KB tiles
    __shared__ float wsum[4];

    int sub = w * 2048;
    int laneoff = ((lane >> 3) << 7) + ((r7 ^ (lane >> 3)) << 4);
    const char* gB = (const char*)(B + (size_t)(tc * 4096) * D);

    // Swizzled ds_read offsets (measured conflict-free R6-R12)
    int off0 = wc * 4096 + r * 128 + ((q ^ r7) << 4);        // kc=0
    int off1 = wc * 4096 + r * 128 + (((4 + q) ^ r7) << 4);  // kc=1

    // Prologue: stage tiles 0,1 into ring slots 0,1
    {
        const char* g0 = gB + sub + laneoff;
        gload_lds16(g0,        lds + sub);
        gload_lds16(g0 + 1024, lds + sub + 1024);
        const char* g1 = gB + 8192 + sub + laneoff;
        gload_lds16(g1,        lds + 8192 + sub);
        gload_lds16(g1 + 1024, lds + 8192 + sub + 1024);
    }

    // Loop-invariant A fragments and negated row-norm constants
    bf16x8 afrag[2][2];
    #pragma unroll
    for (int mt = 0; mt < 2; ++mt)
        #pragma unroll
        for (int kc = 0; kc < 2; ++kc)
            afrag[mt][kc] = *reinterpret_cast<const bf16x8*>(
                A + (size_t)(rowBase + mt * 16 + r) * D + kc * 32 + q * 8);
    f32x4 ncam[2];
    #pragma unroll
    for (int mt = 0; mt < 2; ++mt)
        #pragma unroll
        for (int e = 0; e < 4; ++e)
            ncam[mt][e] = -ca[rowBase + mt * 16 + q * 4 + e];

    const float* cbp = cb + tc * 4096 + wc * 32 + r;

    f32x4 lsum = (f32x4)0.0f;
    f32x4 acc0[2][2], acc1[2][2], acc2[2][2];

    // Epilogue of one acc set (register-only; max3-fusable triple tree)
    #define EPI(ACC)                                                          \
    {                                                                         \
        float e0 = fmaxf(fmaxf(ACC[0][0][0], ACC[0][0][1]), ACC[0][0][2]);    \
        float e1 = fmaxf(fmaxf(ACC[0][0][3], ACC[0][1][0]), ACC[0][1][1]);    \
        float e2 = fmaxf(fmaxf(ACC[0][1][2], ACC[0][1][3]), ACC[1][0][0]);    \
        float e3 = fmaxf(fmaxf(ACC[1][0][1], ACC[1][0][2]), ACC[1][0][3]);    \
        float e4 = fmaxf(fmaxf(ACC[1][1][0], ACC[1][1][1]), ACC[1][1][2]);    \
        float e5 = fmaxf(fmaxf(e0, e1), e2);                                  \
        float e6 = fmaxf(fmaxf(e3, e4), ACC[1][1][3]);                        \
        float em = fmaxf(e5, e6);                                             \
        if (__any(em > -30.0f)) {                                             \
            _Pragma("unroll")                                                 \
            for (int mt = 0; mt < 2; ++mt) {                                  \
                _Pragma("unroll")                                             \
                for (int nt = 0; nt < 2; ++nt) {                              \
                    f32x4 ex;                                                 \
                    _Pragma("unroll")                                         \
                    for (int e = 0; e < 4; ++e)                               \
                        ex[e] = __builtin_amdgcn_exp2f(ACC[mt][nt][e]);       \
                    lsum += ex;                                               \
                }                                                             \
            }                                                                 \
        }                                                                     \
    }

    // One pipeline stage for tile t (RB/SB compile-time): sync, cb, stage
    // t+2, ds_read, [epilogue of previous acc in the latency shadow],
    // init+MFMA into ACC.
    #define GSTEP(RB, SB, ACC, DO_EPI, ACCP, TT)                              \
    {                                                                         \
        asm volatile("s_waitcnt vmcnt(2)" ::: "memory");                      \
        __builtin_amdgcn_s_barrier();                                         \
        asm volatile("" ::: "memory");                                        \
        float cb0 = cbp[0], cb1 = cbp[16];                                    \
        int tn = ((TT) + 2 <= 63) ? ((TT) + 2) : 63;                          \
        const char* gs = gB + (size_t)tn * 8192 + sub + laneoff;              \
        gload_lds16(gs,        lds + (SB) + sub);                             \
        gload_lds16(gs + 1024, lds + (SB) + sub + 1024);                      \
        bf16x8 bf00 = *reinterpret_cast<const bf16x8*>(lds + (RB) + off0);    \
        bf16x8 bf01 = *reinterpret_cast<const bf16x8*>(lds + (RB) + off1);    \
        bf16x8 bf10 = *reinterpret_cast<const bf16x8*>(lds + (RB) + 2048 + off0); \
        bf16x8 bf11 = *reinterpret_cast<const bf16x8*>(lds + (RB) + 2048 + off1); \
        if (DO_EPI) EPI(ACCP);                                                \
        ACC[0][0] = ncam[0] - cb0; ACC[0][1] = ncam[0] - cb1;                 \
        ACC[1][0] = ncam[1] - cb0; ACC[1][1] = ncam[1] - cb1;                 \
        ACC[0][0] = __builtin_amdgcn_mfma_f32_16x16x32_bf16(afrag[0][0], bf00, ACC[0][0], 0, 0, 0); \
        ACC[0][1] = __builtin_amdgcn_mfma_f32_16x16x32_bf16(afrag[0][0], bf10, ACC[0][1], 0, 0, 0); \
        ACC[1][0] = __builtin_amdgcn_mfma_f32_16x16x32_bf16(afrag[1][0], bf00, ACC[1][0], 0, 0, 0); \
        ACC[1][1] = __builtin_amdgcn_mfma_f32_16x16x32_bf16(afrag[1][0], bf10, ACC[1][1], 0, 0, 0); \
        ACC[0][0] = __builtin_amdgcn_mfma_f32_16x16x32_bf16(afrag[0][1], bf01, ACC[0][0], 0, 0, 0); \
        ACC[0][1] = __builtin_amdgcn_mfma_f32_16x16x32_bf16(afrag[0][1], bf11, ACC[0][1], 0, 0, 0); \
        ACC[1][0] = __builtin_amdgcn_mfma_f32_16x16x32_bf16(afrag[1][1], bf01, ACC[1][0], 0, 0, 0); \
        ACC[1][1] = __builtin_amdgcn_mfma_f32_16x16x32_bf16(afrag[1][1], bf11, ACC[1][1], 0, 0, 0); \
        cbp += 64;                                                            \
    }

    // t = 0: ring slot 0, no previous epilogue
    GSTEP(0, 16384, acc0, false, acc0, 0)
    // t = 1..63: 21 trips of 3 (slots: t%3 = 1,2,0)
    for (int trip = 0; trip < 21; ++trip) {
        int t1 = 1 + trip * 3;
        GSTEP(8192,  0,     acc1, true, acc0, t1)
        GSTEP(16384, 8192,  acc2, true, acc1, t1 + 1)
        GSTEP(0,     16384, acc0, true, acc2, t1 + 2)
    }
    EPI(acc0)   // final tile's epilogue

    #undef GSTEP
    #undef EPI

    float ls = lsum[0] + lsum[1] + lsum[2] + lsum[3];
    #pragma unroll
    for (int off = 32; off; off >>= 1) ls += __shfl_xor(ls, off);
    if (lane == 0) wsum[w] = ls;
    __syncthreads();
    if (tid == 0)
        atomicAdd(&accs[p], wsum[0] + wsum[1] + wsum[2] + wsum[3]);
}

__global__ void finalize_kernel(const float* __restrict__ accs,
                                float* __restrict__ out) {
    double inv = 1.0 / (8192.0 * 8192.0 * 3.5449077018110318);
    double mxx = accs[0] * inv, mzz = accs[1] * inv, mxz = accs[2] * inv;
    double mxy = accs[3] * inv, myy = accs[4] * inv, myz = accs[5] * inv;
    double r1 = log(3.0 * sqrt(mxx * mzz + 1e-5) / (mxz + 1e-5));
    double r2 = log(3.0 * sqrt(myy * mzz + 1e-5) / (myz + 1e-5));
    double r3 = log(3.0 * sqrt(mxx * myy + 1e-5) / (mxy + 1e-5));
    out[0] = (float)(10.0 * r1 + r2 + 10.0 * r3);
}

extern "C" void kernel_launch(void* const* d_in, const int* in_sizes, int n_in,
                              void* d_out, int out_size, void* d_ws, size_t ws_size,
                              hipStream_t stream) {
    const float* X = (const float*)d_in[0];
    const float* Y = (const float*)d_in[1];
    const float* Z = (const float*)d_in[2];
    char* ws = (char*)d_ws;
    unsigned short* bmat = (unsigned short*)ws;                       // 3 MB
    float* nscl = (float*)(ws + (size_t)3 * N * D * 2);               // 3*8192 f32
    float* accs = (float*)(ws + (size_t)3 * N * D * 2 + (size_t)3 * N * 4);
    float* out = (float*)d_out;

    hipLaunchKernelGGL(init_accs, dim3(1), dim3(64), 0, stream, accs);
    hipLaunchKernelGGL(convert_norm, dim3(3 * N / 4), dim3(256), 0, stream,
                       X, Y, Z, bmat, nscl);
    hipLaunchKernelGGL(gram_kernel, dim3(256, 6), dim3(256), 0, stream,
                       bmat, nscl, accs);
    hipLaunchKernelGGL(finalize_kernel, dim3(1), dim3(1), 0, stream, accs, out);
}

// Round 14
// 68.317 us; speedup vs baseline: 1.6880x; 1.1634x over previous
//
#include <hip/hip_runtime.h>
#include <math.h>

#define N 8192
#define D 64

typedef short bf16x8 __attribute__((ext_vector_type(8)));
typedef float f32x4 __attribute__((ext_vector_type(4)));

__device__ __forceinline__ void gload_lds16(const void* g, void* l) {
    __builtin_amdgcn_global_load_lds(
        (const __attribute__((address_space(1))) void*)g,
        (__attribute__((address_space(3))) void*)l, 16, 0, 0);
}

__global__ void init_accs(float* accs) {
    if (threadIdx.x < 6) accs[threadIdx.x] = 0.0f;
}

// Convert fp32 -> bf16 of (sqrt(log2e)*x); nscl[i] = 0.5*||bf16(s*x)||^2 = log2e*||x||^2/2.
__global__ __launch_bounds__(256) void convert_norm(
        const float* __restrict__ X, const float* __restrict__ Y,
        const float* __restrict__ Z,
        unsigned short* __restrict__ bmat, float* __restrict__ nscl) {
    int wid  = blockIdx.x * 4 + (threadIdx.x >> 6);
    int lane = threadIdx.x & 63;
    int mat  = wid >> 13;
    int row  = wid & 8191;
    const float* src = (mat == 0) ? X : (mat == 1 ? Y : Z);
    float v = src[row * D + lane] * 1.2011224087864498f;  // sqrt(log2(e))
    unsigned int bits = __builtin_bit_cast(unsigned int, v);
    unsigned short us = (unsigned short)((bits + 0x7FFFu + ((bits >> 16) & 1u)) >> 16);
    float f = __builtin_bit_cast(float, (unsigned int)us << 16);
    bmat[(size_t)mat * (N * D) + row * D + lane] = us;
    float sq = f * f;
    #pragma unroll
    for (int off = 32; off; off >>= 1) sq += __shfl_xor(sq, off);
    if (lane == 0) nscl[mat * N + row] = sq * 0.5f;
}

// R13 per-wave body on a 128-row block: 512 threads / 8 waves in 4x2, each
// wave 32 rows x 32 cols per iter; block = 128 rows x 4096 cols in 64 iters
// of 64-col tiles (8 KB). Grid 768 = EXACTLY 3 blocks/CU (zero tail): per-CU
// staged B-traffic halves (8 KB tile feeds 128 rows) and barrier groups drop
// 6->3. Triple-buffered ring, XOR swizzle, per-iter VMEM = [cb x2, stage x1]
// -> steady-state vmcnt(3) (+ raw s_barrier), first iter vmcnt(1). Tile-t
// epilogue (max-tree + exp, thr=-30) pipelined into tile-(t+1)'s ds latency
// shadow via three named acc sets (all compile-time indexed).
__global__ __launch_bounds__(512, 6) void gram_kernel(
        const unsigned short* __restrict__ bmat,
        const float* __restrict__ nscl,
        float* __restrict__ accs) {
    const int PA[6] = {0, 2, 0, 0, 1, 1};  // X,Z,X,X,Y,Y
    const int PB[6] = {0, 2, 2, 1, 1, 2};  // X,Z,Z,Y,Y,Z
    int p  = blockIdx.y;
    int bx = blockIdx.x;          // 0..127
    int ti = bx >> 1;             // row strip (128 rows)
    int tc = bx & 1;              // col half (4096 cols)

    const unsigned short* A = bmat + (size_t)PA[p] * (N * D);
    const unsigned short* B = bmat + (size_t)PB[p] * (N * D);
    const float* ca = nscl + PA[p] * N;
    const float* cb = nscl + PB[p] * N;

    int tid = threadIdx.x;
    int w = tid >> 6, lane = tid & 63;   // w = 0..7
    int wr = w >> 1, wc = w & 1;         // 4 row-groups x 2 col-groups
    int rowBase = ti * 128 + wr * 32;
    int r = lane & 15, q = lane >> 4, r7 = lane & 7;

    __shared__ __align__(128) char lds[3 * 8192];   // triple-buffered 8 KB tiles
    __shared__ float wsum[8];

    int sub = w * 1024;                   // wave stages 1 KB (8 cols)
    int laneoff = ((lane >> 3) << 7) + ((r7 ^ (lane >> 3)) << 4);
    const char* gB = (const char*)(B + (size_t)(tc * 4096) * D);

    // Swizzled ds_read offsets (measured conflict-free R6-R13)
    int off0 = wc * 4096 + r * 128 + ((q ^ r7) << 4);        // kc=0
    int off1 = wc * 4096 + r * 128 + (((4 + q) ^ r7) << 4);  // kc=1

    // Prologue: stage tiles 0,1 into ring slots 0,1 (1 load/wave each)
    {
        gload_lds16(gB + sub + laneoff,        lds + sub);
        gload_lds16(gB + 8192 + sub + laneoff, lds + 8192 + sub);
    }

    // Loop-invariant A fragments and negated row-norm constants
    bf16x8 afrag[2][2];
    #pragma unroll
    for (int mt = 0; mt < 2; ++mt)
        #pragma unroll
        for (int kc = 0; kc < 2; ++kc)
            afrag[mt][kc] = *reinterpret_cast<const bf16x8*>(
                A + (size_t)(rowBase + mt * 16 + r) * D + kc * 32 + q * 8);
    f32x4 ncam[2];
    #pragma unroll
    for (int mt = 0; mt < 2; ++mt)
        #pragma unroll
        for (int e = 0; e < 4; ++e)
            ncam[mt][e] = -ca[rowBase + mt * 16 + q * 4 + e];

    const float* cbp = cb + tc * 4096 + wc * 32 + r;

    f32x4 lsum = (f32x4)0.0f;
    f32x4 acc0[2][2], acc1[2][2], acc2[2][2];

    // Epilogue of one acc set (register-only; max3-fusable triple tree)
    #define EPI(ACC)                                                          \
    {                                                                         \
        float e0 = fmaxf(fmaxf(ACC[0][0][0], ACC[0][0][1]), ACC[0][0][2]);    \
        float e1 = fmaxf(fmaxf(ACC[0][0][3], ACC[0][1][0]), ACC[0][1][1]);    \
        float e2 = fmaxf(fmaxf(ACC[0][1][2], ACC[0][1][3]), ACC[1][0][0]);    \
        float e3 = fmaxf(fmaxf(ACC[1][0][1], ACC[1][0][2]), ACC[1][0][3]);    \
        float e4 = fmaxf(fmaxf(ACC[1][1][0], ACC[1][1][1]), ACC[1][1][2]);    \
        float e5 = fmaxf(fmaxf(e0, e1), e2);                                  \
        float e6 = fmaxf(fmaxf(e3, e4), ACC[1][1][3]);                        \
        float em = fmaxf(e5, e6);                                             \
        if (__any(em > -30.0f)) {                                             \
            _Pragma("unroll")                                                 \
            for (int mt = 0; mt < 2; ++mt) {                                  \
                _Pragma("unroll")                                             \
                for (int nt = 0; nt < 2; ++nt) {                              \
                    f32x4 ex;                                                 \
                    _Pragma("unroll")                                         \
                    for (int e = 0; e < 4; ++e)                               \
                        ex[e] = __builtin_amdgcn_exp2f(ACC[mt][nt][e]);       \
                    lsum += ex;                                               \
                }                                                             \
            }                                                                 \
        }                                                                     \
    }

    // One pipeline stage for tile t (RB/SB/WAIT compile-time): sync, cb,
    // stage t+2 (1 load), ds_read, [previous tile's epilogue in the latency
    // shadow], init+MFMA into ACC.
    #define GSTEP(RB, SB, ACC, DO_EPI, ACCP, TT, WAITN)                       \
    {                                                                         \
        asm volatile("s_waitcnt vmcnt(" #WAITN ")" ::: "memory");             \
        __builtin_amdgcn_s_barrier();                                         \
        asm volatile("" ::: "memory");                                        \
        float cb0 = cbp[0], cb1 = cbp[16];                                    \
        int tn = ((TT) + 2 <= 63) ? ((TT) + 2) : 63;                          \
        gload_lds16(gB + (size_t)tn * 8192 + sub + laneoff, lds + (SB) + sub);\
        bf16x8 bf00 = *reinterpret_cast<const bf16x8*>(lds + (RB) + off0);    \
        bf16x8 bf01 = *reinterpret_cast<const bf16x8*>(lds + (RB) + off1);    \
        bf16x8 bf10 = *reinterpret_cast<const bf16x8*>(lds + (RB) + 2048 + off0); \
        bf16x8 bf11 = *reinterpret_cast<const bf16x8*>(lds + (RB) + 2048 + off1); \
        if (DO_EPI) EPI(ACCP);                                                \
        ACC[0][0] = ncam[0] - cb0; ACC[0][1] = ncam[0] - cb1;                 \
        ACC[1][0] = ncam[1] - cb0; ACC[1][1] = ncam[1] - cb1;                 \
        ACC[0][0] = __builtin_amdgcn_mfma_f32_16x16x32_bf16(afrag[0][0], bf00, ACC[0][0], 0, 0, 0); \
        ACC[0][1] = __builtin_amdgcn_mfma_f32_16x16x32_bf16(afrag[0][0], bf10, ACC[0][1], 0, 0, 0); \
        ACC[1][0] = __builtin_amdgcn_mfma_f32_16x16x32_bf16(afrag[1][0], bf00, ACC[1][0], 0, 0, 0); \
        ACC[1][1] = __builtin_amdgcn_mfma_f32_16x16x32_bf16(afrag[1][0], bf10, ACC[1][1], 0, 0, 0); \
        ACC[0][0] = __builtin_amdgcn_mfma_f32_16x16x32_bf16(afrag[0][1], bf01, ACC[0][0], 0, 0, 0); \
        ACC[0][1] = __builtin_amdgcn_mfma_f32_16x16x32_bf16(afrag[0][1], bf11, ACC[0][1], 0, 0, 0); \
        ACC[1][0] = __builtin_amdgcn_mfma_f32_16x16x32_bf16(afrag[1][1], bf01, ACC[1][0], 0, 0, 0); \
        ACC[1][1] = __builtin_amdgcn_mfma_f32_16x16x32_bf16(afrag[1][1], bf11, ACC[1][1], 0, 0, 0); \
        cbp += 64;                                                            \
    }

    // t = 0: ring slot 0; only prologue's 2 stage loads outstanding -> need
    // tile 0 retired => vmcnt(1). No previous epilogue.
    GSTEP(0, 16384, acc0, false, acc0, 0, 1)
    // t = 1..63: steady-state vmcnt(3); 21 trips of 3 (slots 1,2,0)
    for (int trip = 0; trip < 21; ++trip) {
        int t1 = 1 + trip * 3;
        GSTEP(8192,  0,     acc1, true, acc0, t1,     3)
        GSTEP(16384, 8192,  acc2, true, acc1, t1 + 1, 3)
        GSTEP(0,     16384, acc0, true, acc2, t1 + 2, 3)
    }
    EPI(acc0)   // final tile's epilogue

    #undef GSTEP
    #undef EPI

    float ls = lsum[0] + lsum[1] + lsum[2] + lsum[3];
    #pragma unroll
    for (int off = 32; off; off >>= 1) ls += __shfl_xor(ls, off);
    if (lane == 0) wsum[w] = ls;
    __syncthreads();
    if (tid == 0) {
        float s = 0.0f;
        #pragma unroll
        for (int i = 0; i < 8; ++i) s += wsum[i];
        atomicAdd(&accs[p], s);
    }
}

__global__ void finalize_kernel(const float* __restrict__ accs,
                                float* __restrict__ out) {
    double inv = 1.0 / (8192.0 * 8192.0 * 3.5449077018110318);
    double mxx = accs[0] * inv, mzz = accs[1] * inv, mxz = accs[2] * inv;
    double mxy = accs[3] * inv, myy = accs[4] * inv, myz = accs[5] * inv;
    double r1 = log(3.0 * sqrt(mxx * mzz + 1e-5) / (mxz + 1e-5));
    double r2 = log(3.0 * sqrt(myy * mzz + 1e-5) / (myz + 1e-5));
    double r3 = log(3.0 * sqrt(mxx * myy + 1e-5) / (mxy + 1e-5));
    out[0] = (float)(10.0 * r1 + r2 + 10.0 * r3);
}

extern "C" void kernel_launch(void* const* d_in, const int* in_sizes, int n_in,
                              void* d_out, int out_size, void* d_ws, size_t ws_size,
                              hipStream_t stream) {
    const float* X = (const float*)d_in[0];
    const float* Y = (const float*)d_in[1];
    const float* Z = (const float*)d_in[2];
    char* ws = (char*)d_ws;
    unsigned short* bmat = (unsigned short*)ws;                       // 3 MB
    float* nscl = (float*)(ws + (size_t)3 * N * D * 2);               // 3*8192 f32
    float* accs = (float*)(ws + (size_t)3 * N * D * 2 + (size_t)3 * N * 4);
    float* out = (float*)d_out;

    hipLaunchKernelGGL(init_accs, dim3(1), dim3(64), 0, stream, accs);
    hipLaunchKernelGGL(convert_norm, dim3(3 * N / 4), dim3(256), 0, stream,
                       X, Y, Z, bmat, nscl);
    hipLaunchKernelGGL(gram_kernel, dim3(128, 6), dim3(512), 0, stream,
                       bmat, nscl, accs);
    hipLaunchKernelGGL(finalize_kernel, dim3(1), dim3(1), 0, stream, accs, out);
}